// Round 2
// baseline (478.765 us; speedup 1.0000x reference)
//
#include <hip/hip_runtime.h>
#include <cstdint>

typedef short bf16x8 __attribute__((ext_vector_type(8)));
typedef float f32x4  __attribute__((ext_vector_type(4)));

#define DIM   1024
#define NROWS 32768

__device__ __forceinline__ ushort f2bf(float f){
  union { float f; uint32_t u; } v; v.f = f;
  uint32_t u = v.u;
  return (ushort)((u + 0x7fffu + ((u >> 16) & 1u)) >> 16);  // RNE
}

// ---------------- LayerNorm: one wave per row, 4 rows/block ----------------
__global__ void ln_kernel(const float* __restrict__ x,
                          const float* __restrict__ gamma,
                          const float* __restrict__ beta,
                          ushort* __restrict__ h){
  const int w = threadIdx.x >> 6;
  const int l = threadIdx.x & 63;
  const int row = blockIdx.x * 4 + w;
  const float4* xr = (const float4*)(x + (size_t)row * DIM);
  float4 v[4];
  float s = 0.f, ss = 0.f;
#pragma unroll
  for (int i = 0; i < 4; ++i){
    v[i] = xr[i * 64 + l];
    s  += v[i].x + v[i].y + v[i].z + v[i].w;
    ss += v[i].x * v[i].x + v[i].y * v[i].y + v[i].z * v[i].z + v[i].w * v[i].w;
  }
#pragma unroll
  for (int m = 1; m < 64; m <<= 1){
    s  += __shfl_xor(s,  m, 64);
    ss += __shfl_xor(ss, m, 64);
  }
  const float mean = s * (1.f / 1024.f);
  const float var  = ss * (1.f / 1024.f) - mean * mean;
  const float rstd = rsqrtf(var + 1e-5f);
  ushort* hr = h + (size_t)row * DIM;
#pragma unroll
  for (int i = 0; i < 4; ++i){
    const int c = (i * 64 + l) * 4;
    float4 gm = ((const float4*)gamma)[i * 64 + l];
    float4 bt = ((const float4*)beta )[i * 64 + l];
    ushort4 o;
    o.x = f2bf((v[i].x - mean) * rstd * gm.x + bt.x);
    o.y = f2bf((v[i].y - mean) * rstd * gm.y + bt.y);
    o.z = f2bf((v[i].z - mean) * rstd * gm.z + bt.z);
    o.w = f2bf((v[i].w - mean) * rstd * gm.w + bt.w);
    *(ushort4*)(hr + c) = o;
  }
}

// -------- W [1024][2048] f32  ->  Wt [2048][1024] bf16 (tiled transpose) ----
__global__ void wt_kernel(const float* __restrict__ W, ushort* __restrict__ Wt){
  __shared__ float tile[64][65];
  const int t  = threadIdx.x;
  const int k0 = blockIdx.x * 64;
  const int n0 = blockIdx.y * 64;
  const int lr = t >> 4;         // 0..15
  const int lc = (t & 15) * 4;   // 0..60
#pragma unroll
  for (int p = 0; p < 4; ++p){
    const int kk = p * 16 + lr;
    float4 val = *(const float4*)(W + (size_t)(k0 + kk) * 2048 + n0 + lc);
    tile[kk][lc + 0] = val.x; tile[kk][lc + 1] = val.y;
    tile[kk][lc + 2] = val.z; tile[kk][lc + 3] = val.w;
  }
  __syncthreads();
#pragma unroll
  for (int p = 0; p < 4; ++p){
    const int nn = p * 16 + lr;
    ushort4 o;
    o.x = f2bf(tile[lc + 0][nn]);
    o.y = f2bf(tile[lc + 1][nn]);
    o.z = f2bf(tile[lc + 2][nn]);
    o.w = f2bf(tile[lc + 3][nn]);
    *(ushort4*)(Wt + (size_t)(n0 + nn) * 1024 + k0 + lc) = o;
  }
}

// ---------------- fused GEMM (v & g paired) + GLU + residual ----------------
// Block: 128 rows x (64 v-cols + paired 64 g-cols). 256 thr = 4 waves,
// wave w owns rows [w*32, w*32+32), all 128 effective cols.
__global__ __launch_bounds__(256)
void glu_gemm(const ushort* __restrict__ hA,   // [32768][1024] bf16
              const ushort* __restrict__ Wt,   // [2048][1024]  bf16
              const float*  __restrict__ bias, // [2048]
              const float*  __restrict__ x,    // [32768][1024] f32
              float* __restrict__ out){        // [32768][1024] f32
  __shared__ ushort As[128][64];
  __shared__ ushort Bs[128][64];   // rows 0..63: v cols, 64..127: paired g cols

  const int w = threadIdx.x >> 6;
  const int l = threadIdx.x & 63;
  const int brow  = blockIdx.x * 128;
  const int ncol0 = blockIdx.y * 64;

  f32x4 acc[2][8];
  const f32x4 zero = {0.f, 0.f, 0.f, 0.f};
#pragma unroll
  for (int i = 0; i < 2; ++i)
#pragma unroll
    for (int j = 0; j < 8; ++j) acc[i][j] = zero;

  const int lr8 = l >> 3;        // 0..7 (row within 8-row stripe)
  const int lc8 = (l & 7) * 8;   // bf16 element offset (16B per lane)

  for (int kt = 0; kt < 16; ++kt){
    const int k0 = kt * 64;
    // stage A tile: 128 rows x 64 bf16, linear LDS, 1 KiB per wave-instr
#pragma unroll
    for (int i = 0; i < 4; ++i){
      const int rbase = i * 32 + w * 8;
      const ushort* gp = hA + (size_t)(brow + rbase + lr8) * 1024 + k0 + lc8;
      __builtin_amdgcn_global_load_lds((const __attribute__((address_space(1))) void*)gp,
                                       (__attribute__((address_space(3))) void*)&As[rbase][0],
                                       16, 0, 0);
    }
    // stage B tile: rows t<64 -> Wt[ncol0+t], t>=64 -> Wt[1024+ncol0+t-64]
#pragma unroll
    for (int i = 0; i < 4; ++i){
      const int rbase = i * 32 + w * 8;
      const int tt = rbase + lr8;
      const int wrow = ncol0 + tt + ((tt >> 6) * 960);   // branchless: tt>=64 -> +960
      const ushort* gp = Wt + (size_t)wrow * 1024 + k0 + lc8;
      __builtin_amdgcn_global_load_lds((const __attribute__((address_space(1))) void*)gp,
                                       (__attribute__((address_space(3))) void*)&Bs[rbase][0],
                                       16, 0, 0);
    }
    __syncthreads();   // compiler drains vmcnt before s_barrier -> tiles ready
#pragma unroll
    for (int ks = 0; ks < 2; ++ks){
      bf16x8 a[2], b[8];
      const int ko = ks * 32 + ((l >> 4) << 3);
#pragma unroll
      for (int mi = 0; mi < 2; ++mi)
        a[mi] = *(const bf16x8*)&As[w * 32 + mi * 16 + (l & 15)][ko];
#pragma unroll
      for (int ni = 0; ni < 8; ++ni)
        b[ni] = *(const bf16x8*)&Bs[ni * 16 + (l & 15)][ko];
#pragma unroll
      for (int mi = 0; mi < 2; ++mi)
#pragma unroll
        for (int ni = 0; ni < 8; ++ni)
          acc[mi][ni] = __builtin_amdgcn_mfma_f32_16x16x32_bf16(a[mi], b[ni], acc[mi][ni], 0, 0, 0);
    }
    __syncthreads();   // all waves done reading before next stage overwrites
  }

  // epilogue: out = x + (v + b_v) * sigmoid(g + b_g)
  // C/D layout (m89-verified): col = lane&15, row = (lane>>4)*4 + reg
  float bv[4], bg[4];
#pragma unroll
  for (int ni = 0; ni < 4; ++ni){
    const int col = ncol0 + ni * 16 + (l & 15);
    bv[ni] = bias[col];
    bg[ni] = bias[col + 1024];
  }
  const int rb = brow + w * 32 + ((l >> 4) << 2);
#pragma unroll
  for (int mi = 0; mi < 2; ++mi){
#pragma unroll
    for (int r = 0; r < 4; ++r){
      const int row = rb + mi * 16 + r;
      const float* xrow = x   + (size_t)row * 1024;
      float*       orow = out + (size_t)row * 1024;
#pragma unroll
      for (int ni = 0; ni < 4; ++ni){
        const int col = ncol0 + ni * 16 + (l & 15);
        const float vv = acc[mi][ni    ][r] + bv[ni];
        const float gg = acc[mi][ni + 4][r] + bg[ni];
        const float sg = 1.f / (1.f + __expf(-gg));
        orow[col] = xrow[col] + vv * sg;
      }
    }
  }
}

extern "C" void kernel_launch(void* const* d_in, const int* in_sizes, int n_in,
                              void* d_out, int out_size, void* d_ws, size_t ws_size,
                              hipStream_t stream){
  const float* x     = (const float*)d_in[0];
  const float* gamma = (const float*)d_in[1];
  const float* beta  = (const float*)d_in[2];
  const float* W     = (const float*)d_in[3];
  const float* b     = (const float*)d_in[4];
  float* out = (float*)d_out;

  ushort* h  = (ushort*)d_ws;                                    // 64 MB bf16
  ushort* Wt = (ushort*)((char*)d_ws + (size_t)NROWS * DIM * 2); // 4 MB bf16

  ln_kernel<<<NROWS / 4, 256, 0, stream>>>(x, gamma, beta, h);
  wt_kernel<<<dim3(16, 32), 256, 0, stream>>>(W, Wt);
  glu_gemm<<<dim3(NROWS / 128, 16), 256, 0, stream>>>(h, Wt, b, x, out);
}

// Round 4
// 389.998 us; speedup vs baseline: 1.2276x; 1.2276x over previous
//
#include <hip/hip_runtime.h>
#include <cstdint>

typedef short bf16x8 __attribute__((ext_vector_type(8)));
typedef float f32x4  __attribute__((ext_vector_type(4)));

#define DIM   1024
#define NROWS 32768

__device__ __forceinline__ ushort f2bf(float f){
  union { float f; uint32_t u; } v; v.f = f;
  uint32_t u = v.u;
  return (ushort)((u + 0x7fffu + ((u >> 16) & 1u)) >> 16);  // RNE
}

// ---------------- LayerNorm: one wave per row, 4 rows/block ----------------
__global__ void ln_kernel(const float* __restrict__ x,
                          const float* __restrict__ gamma,
                          const float* __restrict__ beta,
                          ushort* __restrict__ h){
  const int w = threadIdx.x >> 6;
  const int l = threadIdx.x & 63;
  const int row = blockIdx.x * 4 + w;
  const float4* xr = (const float4*)(x + (size_t)row * DIM);
  float4 v[4];
  float s = 0.f, ss = 0.f;
#pragma unroll
  for (int i = 0; i < 4; ++i){
    v[i] = xr[i * 64 + l];
    s  += v[i].x + v[i].y + v[i].z + v[i].w;
    ss += v[i].x * v[i].x + v[i].y * v[i].y + v[i].z * v[i].z + v[i].w * v[i].w;
  }
#pragma unroll
  for (int m = 1; m < 64; m <<= 1){
    s  += __shfl_xor(s,  m, 64);
    ss += __shfl_xor(ss, m, 64);
  }
  const float mean = s * (1.f / 1024.f);
  const float var  = ss * (1.f / 1024.f) - mean * mean;
  const float rstd = rsqrtf(var + 1e-5f);
  ushort* hr = h + (size_t)row * DIM;
#pragma unroll
  for (int i = 0; i < 4; ++i){
    const int c = (i * 64 + l) * 4;
    float4 gm = ((const float4*)gamma)[i * 64 + l];
    float4 bt = ((const float4*)beta )[i * 64 + l];
    ushort4 o;
    o.x = f2bf((v[i].x - mean) * rstd * gm.x + bt.x);
    o.y = f2bf((v[i].y - mean) * rstd * gm.y + bt.y);
    o.z = f2bf((v[i].z - mean) * rstd * gm.z + bt.z);
    o.w = f2bf((v[i].w - mean) * rstd * gm.w + bt.w);
    *(ushort4*)(hr + c) = o;
  }
}

// -------- W [1024][2048] f32  ->  Wt [2048][1024] bf16 (tiled transpose) ----
__global__ void wt_kernel(const float* __restrict__ W, ushort* __restrict__ Wt){
  __shared__ float tile[64][65];
  const int t  = threadIdx.x;
  const int k0 = blockIdx.x * 64;
  const int n0 = blockIdx.y * 64;
  const int lr = t >> 4;
  const int lc = (t & 15) * 4;
#pragma unroll
  for (int p = 0; p < 4; ++p){
    const int kk = p * 16 + lr;
    float4 val = *(const float4*)(W + (size_t)(k0 + kk) * 2048 + n0 + lc);
    tile[kk][lc + 0] = val.x; tile[kk][lc + 1] = val.y;
    tile[kk][lc + 2] = val.z; tile[kk][lc + 3] = val.w;
  }
  __syncthreads();
#pragma unroll
  for (int p = 0; p < 4; ++p){
    const int nn = p * 16 + lr;
    ushort4 o;
    o.x = f2bf(tile[lc + 0][nn]);
    o.y = f2bf(tile[lc + 1][nn]);
    o.z = f2bf(tile[lc + 2][nn]);
    o.w = f2bf(tile[lc + 3][nn]);
    *(ushort4*)(Wt + (size_t)(n0 + nn) * 1024 + k0 + lc) = o;
  }
}

// ---------------- fused GEMM (v & g paired) + GLU + residual ----------------
// BM=128 rows x 128 eff-cols (B-tile = 256 rows: 128 v + 128 g). BK=64.
// 512 thr = 8 waves (2 M x 4 N); wave owns 64 rows x 32 eff-cols; acc[4][4].
// 3-slot LDS pipeline (48 KB/slot), counted vmcnt(6), XOR-swizzled LDS (T2,
// both-sides: pre-swizzled global source + swizzled ds_read, LDS linear).
#define SLOT_U   24576   // ushorts per slot (A 8192 + B 16384)
#define B_OFF    8192

__global__ __launch_bounds__(512, 2)
void glu_gemm(const ushort* __restrict__ hA,   // [32768][1024] bf16
              const ushort* __restrict__ Wt,   // [2048][1024]  bf16
              const float*  __restrict__ bias, // [2048]
              const float*  __restrict__ x,    // [32768][1024] f32
              float* __restrict__ out){        // [32768][1024] f32
  __shared__ ushort smem[3 * SLOT_U];          // 144 KB

  const int tid = threadIdx.x;
  const int l   = tid & 63;
  const int w   = tid >> 6;      // wave 0..7
  const int wm  = w >> 2;        // 0..1
  const int wn  = w & 3;         // 0..3

  // T1: bijective XCD swizzle (nwg=2048, 2048%8==0)
  const int bid = blockIdx.x;
  const int sw  = (bid & 7) * 256 + (bid >> 3);
  const int bm  = sw >> 3;               // 0..255
  const int bn  = sw & 7;                // 0..7
  const int brow  = bm * 128;
  const int ncol0 = bn * 128;

  // staging lane mapping: 512 thr, 16B/load; row-group rg, chunk c
  const int rg = tid >> 3;               // 0..63
  const int c  = tid & 7;                // 16B chunk within 128B row

  auto stageA = [&](int kt, int slot){
    const int k0 = kt * 64;
#pragma unroll
    for (int i = 0; i < 2; ++i){
      const int r = i * 64 + rg;                       // 0..127
      const ushort* gp = hA + (size_t)(brow + r) * 1024 + k0 + ((c ^ (r & 7)) * 8);
      ushort* lp = &smem[slot * SLOT_U + (i * 64 + w * 8) * 64];
      __builtin_amdgcn_global_load_lds((const __attribute__((address_space(1))) void*)gp,
                                       (__attribute__((address_space(3))) void*)lp, 16, 0, 0);
    }
  };
  auto stageB = [&](int kt, int slot, int j){          // one of 4 issues
    const int k0 = kt * 64;
    const int tB = j * 64 + rg;                        // 0..255
    const int wrow = ncol0 + (tB & 127) + ((tB >> 7) * 1024);
    const ushort* gp = Wt + (size_t)wrow * 1024 + k0 + ((c ^ (tB & 7)) * 8);
    ushort* lp = &smem[slot * SLOT_U + B_OFF + (j * 64 + w * 8) * 64];
    __builtin_amdgcn_global_load_lds((const __attribute__((address_space(1))) void*)gp,
                                     (__attribute__((address_space(3))) void*)lp, 16, 0, 0);
  };

  auto readA = [&](int slot, int m, int kk) -> bf16x8 {
    const int R  = wm * 64 + m * 16 + (l & 15);
    const int pc = (kk * 4 + (l >> 4)) ^ (l & 7);      // R&7 == l&7
    return *(const bf16x8*)&smem[slot * SLOT_U + R * 64 + pc * 8];
  };
  auto readB = [&](int slot, int nf, int kk) -> bf16x8 {
    const int Br = (nf >> 1) * 128 + wn * 32 + (nf & 1) * 16 + (l & 15);
    const int pc = (kk * 4 + (l >> 4)) ^ (l & 7);      // Br&7 == l&7
    return *(const bf16x8*)&smem[slot * SLOT_U + B_OFF + Br * 64 + pc * 8];
  };

  f32x4 acc[4][4];
  const f32x4 zero = {0.f, 0.f, 0.f, 0.f};
#pragma unroll
  for (int i = 0; i < 4; ++i)
#pragma unroll
    for (int j = 0; j < 4; ++j) acc[i][j] = zero;

  // ---- prologue: stage K-tiles 0 and 1 ----
  stageA(0, 0);
#pragma unroll
  for (int j = 0; j < 4; ++j) stageB(0, 0, j);
  stageA(1, 1);
#pragma unroll
  for (int j = 0; j < 4; ++j) stageB(1, 1, j);
  asm volatile("s_waitcnt vmcnt(6)" ::: "memory");     // K-tile 0 resident
  __builtin_amdgcn_s_barrier();
  __builtin_amdgcn_sched_barrier(0);

  // ---- main loop: 16 K-tiles, 2 phases each, counted vmcnt per tile ----
#pragma unroll
  for (int kt = 0; kt < 16; ++kt){
    const int slot  = kt % 3;
    const int pslot = (kt + 2) % 3;                    // freed at end of kt-1
    const bool do_stage = (kt < 14);

    // phase 0: all B frags + A m{0,1}; issue 3 prefetch loads; 16 MFMA
    bf16x8 bfr[4][2], a0[2][2];
#pragma unroll
    for (int nf = 0; nf < 4; ++nf)
#pragma unroll
      for (int kk = 0; kk < 2; ++kk) bfr[nf][kk] = readB(slot, nf, kk);
#pragma unroll
    for (int m = 0; m < 2; ++m)
#pragma unroll
      for (int kk = 0; kk < 2; ++kk) a0[m][kk] = readA(slot, m, kk);
    if (do_stage){ stageA(kt + 2, pslot); stageB(kt + 2, pslot, 0); }
    __builtin_amdgcn_s_setprio(1);
#pragma unroll
    for (int m = 0; m < 2; ++m)
#pragma unroll
      for (int nf = 0; nf < 4; ++nf)
#pragma unroll
        for (int kk = 0; kk < 2; ++kk)
          acc[m][nf] = __builtin_amdgcn_mfma_f32_16x16x32_bf16(a0[m][kk], bfr[nf][kk], acc[m][nf], 0, 0, 0);
    __builtin_amdgcn_s_setprio(0);

    // phase 1: A m{2,3}; issue remaining 3 prefetch loads; 16 MFMA
    bf16x8 a1[2][2];
#pragma unroll
    for (int m = 0; m < 2; ++m)
#pragma unroll
      for (int kk = 0; kk < 2; ++kk) a1[m][kk] = readA(slot, m + 2, kk);
    if (do_stage){ stageB(kt + 2, pslot, 1); stageB(kt + 2, pslot, 2); stageB(kt + 2, pslot, 3); }
    __builtin_amdgcn_s_setprio(1);
#pragma unroll
    for (int m = 0; m < 2; ++m)
#pragma unroll
      for (int nf = 0; nf < 4; ++nf)
#pragma unroll
        for (int kk = 0; kk < 2; ++kk)
          acc[m + 2][nf] = __builtin_amdgcn_mfma_f32_16x16x32_bf16(a1[m][kk], bfr[nf][kk], acc[m + 2][nf], 0, 0, 0);
    __builtin_amdgcn_s_setprio(0);

    // boundary: counted vmcnt (T4), raw barrier, sched fences
    if (kt < 15){
      __builtin_amdgcn_sched_barrier(0);
      if (kt < 14) asm volatile("s_waitcnt vmcnt(6)" ::: "memory");
      else         asm volatile("s_waitcnt vmcnt(0)" ::: "memory");   // tail drain
      __builtin_amdgcn_s_barrier();
      __builtin_amdgcn_sched_barrier(0);
    }
  }

  // ---- epilogue: out = x + (v + b_v) * sigmoid(g + b_g) ----
  // C/D layout: col = lane&15, row = (lane>>4)*4 + reg (m89-verified)
  float bv[2], bg[2];
#pragma unroll
  for (int n = 0; n < 2; ++n){
    const int col = ncol0 + wn * 32 + n * 16 + (l & 15);
    bv[n] = bias[col];
    bg[n] = bias[col + 1024];
  }
  const int rb = brow + wm * 64 + ((l >> 4) << 2);
#pragma unroll
  for (int m = 0; m < 4; ++m){
#pragma unroll
    for (int r = 0; r < 4; ++r){
      const int row = rb + m * 16 + r;
      const float* xrow = x   + (size_t)row * 1024;
      float*       orow = out + (size_t)row * 1024;
#pragma unroll
      for (int n = 0; n < 2; ++n){
        const int col = ncol0 + wn * 32 + n * 16 + (l & 15);
        const float vv = acc[m][n    ][r] + bv[n];
        const float gg = acc[m][n + 2][r] + bg[n];
        const float sg = 1.f / (1.f + __expf(-gg));
        orow[col] = xrow[col] + vv * sg;
      }
    }
  }
}

extern "C" void kernel_launch(void* const* d_in, const int* in_sizes, int n_in,
                              void* d_out, int out_size, void* d_ws, size_t ws_size,
                              hipStream_t stream){
  const float* x     = (const float*)d_in[0];
  const float* gamma = (const float*)d_in[1];
  const float* beta  = (const float*)d_in[2];
  const float* W     = (const float*)d_in[3];
  const float* b     = (const float*)d_in[4];
  float* out = (float*)d_out;

  ushort* h  = (ushort*)d_ws;                                    // 64 MB bf16
  ushort* Wt = (ushort*)((char*)d_ws + (size_t)NROWS * DIM * 2); // 4 MB bf16

  ln_kernel<<<NROWS / 4, 256, 0, stream>>>(x, gamma, beta, h);
  wt_kernel<<<dim3(16, 32), 256, 0, stream>>>(W, Wt);
  glu_gemm<<<2048, 512, 0, stream>>>(h, Wt, b, x, out);
}